// Round 1
// baseline (474.600 us; speedup 1.0000x reference)
//
#include <hip/hip_runtime.h>
#include <stdint.h>

#define N 8192
#define FD 64
#define NC 10

typedef __attribute__((ext_vector_type(8))) __bf16 bf16x8;
typedef __attribute__((ext_vector_type(4))) float f32x4;

__device__ __forceinline__ unsigned short f2bf(float f) {
    unsigned u = __builtin_bit_cast(unsigned, f);
    u += 0x7fffu + ((u >> 16) & 1u);   // round-to-nearest-even
    return (unsigned short)(u >> 16);
}

// ---------------------------------------------------------------------------
// Kernel 1: fused row-sum of fp32 A + cast A -> bf16 (RNE). One block per row.
// ---------------------------------------------------------------------------
__global__ __launch_bounds__(256) void rowsum_cast(const float* __restrict__ A,
                                                   unsigned short* __restrict__ Abf,
                                                   float* __restrict__ dvec) {
    const int row = blockIdx.x;
    const int t = threadIdx.x;
    const float4* Arow = (const float4*)(A + (size_t)row * N);
    ushort4* Brow = (ushort4*)(Abf + (size_t)row * N);
    float s = 0.f;
#pragma unroll
    for (int i = 0; i < 8; i++) {
        int c4 = t + 256 * i;            // 256 threads * 8 iters = 2048 float4 = 8192 floats
        float4 v = Arow[c4];
        s += (v.x + v.y) + (v.z + v.w);
        ushort4 o;
        o.x = f2bf(v.x); o.y = f2bf(v.y); o.z = f2bf(v.z); o.w = f2bf(v.w);
        Brow[c4] = o;
    }
#pragma unroll
    for (int off = 32; off > 0; off >>= 1) s += __shfl_down(s, off, 64);
    __shared__ float red[4];
    if ((t & 63) == 0) red[t >> 6] = s;
    __syncthreads();
    if (t == 0) {
        float tot = (red[0] + red[1]) + (red[2] + red[3]);
        dvec[row] = tot > 0.f ? rsqrtf(tot) : 0.f;
    }
}

// ---------------------------------------------------------------------------
// Kernel 2: yT[f][r] = bf16( d[r] * sum_j x[r][j] * W[j][f] )   (transposed out)
// Block handles 64 rows. x is fp32 [N][64], W fp32 [64][64].
// ---------------------------------------------------------------------------
__global__ __launch_bounds__(256) void xw_scale(const float* __restrict__ x,
                                                const float* __restrict__ W,
                                                const float* __restrict__ dvec,
                                                unsigned short* __restrict__ yT) {
    __shared__ float Ws[64][65];
    __shared__ float Xs[64][65];
    __shared__ float Ysh[64][65];
    const int t = threadIdx.x;
    const int r0 = blockIdx.x * 64;
#pragma unroll
    for (int i = 0; i < 16; i++) {
        int idx = t + 256 * i;           // 4096 elements
        Ws[idx >> 6][idx & 63] = W[idx];
        Xs[idx >> 6][idx & 63] = x[(size_t)r0 * 64 + idx];
    }
    __syncthreads();
    const int f = t & 63, w = t >> 6;
#pragma unroll
    for (int rr = 0; rr < 16; rr++) {
        int r = w * 16 + rr;
        float acc = 0.f;
#pragma unroll
        for (int j = 0; j < 64; j++) acc += Xs[r][j] * Ws[j][f];
        Ysh[r][f] = dvec[r0 + r] * acc;
    }
    __syncthreads();
    // transposed, coalesced store: lane = r, wave quarter picks f range
    const int rl = t & 63, fq = t >> 6;
#pragma unroll
    for (int ff = 0; ff < 16; ff++) {
        int fi = fq * 16 + ff;
        yT[(size_t)fi * N + r0 + rl] = f2bf(Ysh[rl][fi]);
    }
}

// ---------------------------------------------------------------------------
// Kernel 3: split-K bf16 MFMA GEMM: partial[sk][m][f] = sum_{k in sk-slice} A[m][k]*y[k][f]
// BM=64 rows/block, BK=128, SK=4 (grid.y). 4 waves: wave w owns rows w*16..+15, all 64 f.
// LDS tiles stored as 16B chunks with XOR swizzle (chunk c of row r at c^(r&15))
// so ds_read_b128 fragment reads are bank-conflict-free.
// ---------------------------------------------------------------------------
__global__ __launch_bounds__(256) void spmm(const unsigned short* __restrict__ Abf,
                                            const unsigned short* __restrict__ yT,
                                            float* __restrict__ partial) {
    constexpr int BM = 64, BK = 128, SK = 4;
    constexpr int KS = N / SK;           // 2048
    __shared__ unsigned short As[BM * BK];   // 16 KB
    __shared__ unsigned short Ys[64 * BK];   // 16 KB
    const int t = threadIdx.x;
    const int m0 = blockIdx.x * BM;
    const int kbase = blockIdx.y * KS;
    const int lane = t & 63, w = t >> 6;
    const int quad = lane >> 4, lr = lane & 15;

    f32x4 acc[4];
#pragma unroll
    for (int nt = 0; nt < 4; nt++) { acc[nt].x = 0.f; acc[nt].y = 0.f; acc[nt].z = 0.f; acc[nt].w = 0.f; }

    for (int k0 = kbase; k0 < kbase + KS; k0 += BK) {
        // stage: 64 rows x 16 chunks (16B each) per tile; 256 threads x 4 chunks
#pragma unroll
        for (int p = 0; p < 4; p++) {
            int q = p * 256 + t;
            int row = q >> 4, c = q & 15;
            float4 va = *(const float4*)(Abf + (size_t)(m0 + row) * N + k0 + c * 8);
            *(float4*)(As + (row * 16 + (c ^ (row & 15))) * 8) = va;
            float4 vy = *(const float4*)(yT + (size_t)row * N + k0 + c * 8);
            *(float4*)(Ys + (row * 16 + (c ^ (row & 15))) * 8) = vy;
        }
        __syncthreads();
#pragma unroll
        for (int kk = 0; kk < BK; kk += 32) {
            int cc = (kk >> 3) + quad;
            // A fragment: A[m = w*16+lr][k = kk + quad*8 + j]
            bf16x8 af = *(const bf16x8*)(As + ((w * 16 + lr) * 16 + (cc ^ lr)) * 8);
#pragma unroll
            for (int nt = 0; nt < 4; nt++) {
                // B fragment: B[k][n = nt*16+lr] = yT[n][k]
                bf16x8 bv = *(const bf16x8*)(Ys + ((nt * 16 + lr) * 16 + (cc ^ lr)) * 8);
                acc[nt] = __builtin_amdgcn_mfma_f32_16x16x32_bf16(af, bv, acc[nt], 0, 0, 0);
            }
        }
        __syncthreads();
    }
    // C/D layout: row = quad*4 + r, col = lr  (verified gfx950 mapping)
#pragma unroll
    for (int nt = 0; nt < 4; nt++) {
#pragma unroll
        for (int r = 0; r < 4; r++) {
            int m = m0 + w * 16 + quad * 4 + r;
            int fcol = nt * 16 + lr;
            partial[((size_t)blockIdx.y * N + m) * FD + fcol] = acc[nt][r];
        }
    }
}

// ---------------------------------------------------------------------------
// Kernel 4: x[m][f] = relu( d[m] * sum_sk partial[sk][m][f] )  (fp32 out)
// ---------------------------------------------------------------------------
__global__ __launch_bounds__(256) void combine_relu(const float4* __restrict__ partial,
                                                    const float* __restrict__ dvec,
                                                    float4* __restrict__ xout) {
    const int gid = blockIdx.x * 256 + threadIdx.x;   // < N*FD/4 = 131072
    constexpr int S4 = N * FD / 4;
    float4 a = partial[gid];
    float4 b = partial[gid + S4];
    float4 c = partial[gid + 2 * S4];
    float4 e = partial[gid + 3 * S4];
    float dm = dvec[gid >> 4];                        // 16 float4 per row of 64
    float4 o;
    o.x = fmaxf(0.f, dm * ((a.x + b.x) + (c.x + e.x)));
    o.y = fmaxf(0.f, dm * ((a.y + b.y) + (c.y + e.y)));
    o.z = fmaxf(0.f, dm * ((a.z + b.z) + (c.z + e.z)));
    o.w = fmaxf(0.f, dm * ((a.w + b.w) + (c.w + e.w)));
    xout[gid] = o;
}

// ---------------------------------------------------------------------------
// Kernel 5: logits[m][c] = bc[c] + sum_j x[m][j] * Wc[j][c]
// ---------------------------------------------------------------------------
__global__ __launch_bounds__(256) void logits_k(const float* __restrict__ x2,
                                                const float* __restrict__ Wc,
                                                const float* __restrict__ bc,
                                                float* __restrict__ out) {
    const int id = blockIdx.x * 256 + threadIdx.x;    // < N*NC = 81920
    const int m = id / NC, c = id - m * NC;
    const float* xr = x2 + (size_t)m * FD;
    float acc = bc[c];
#pragma unroll
    for (int j = 0; j < 64; j++) acc += xr[j] * Wc[j * NC + c];
    out[id] = acc;
}

// ---------------------------------------------------------------------------
extern "C" void kernel_launch(void* const* d_in, const int* in_sizes, int n_in,
                              void* d_out, int out_size, void* d_ws, size_t ws_size,
                              hipStream_t stream) {
    const float* A   = (const float*)d_in[0];
    const float* emb = (const float*)d_in[1];
    const float* W1  = (const float*)d_in[2];
    const float* W2  = (const float*)d_in[3];
    const float* Wc  = (const float*)d_in[4];
    const float* bc  = (const float*)d_in[5];
    char* ws = (char*)d_ws;

    // workspace layout (all 16B-aligned)
    unsigned short* Abf  = (unsigned short*)(ws);                 // 134,217,728 B
    float* dvec          = (float*)(ws + 134217728);              //      32,768 B
    unsigned short* yT   = (unsigned short*)(ws + 134250496);     //   1,048,576 B
    float* xbuf          = (float*)(ws + 135299072);              //   2,097,152 B
    float* partial       = (float*)(ws + 137396224);              //   8,388,608 B
    float* out           = (float*)d_out;

    rowsum_cast<<<N, 256, 0, stream>>>(A, Abf, dvec);

    // layer 1
    xw_scale<<<N / 64, 256, 0, stream>>>(emb, W1, dvec, yT);
    spmm<<<dim3(N / 64, 4), 256, 0, stream>>>(Abf, yT, partial);
    combine_relu<<<N * FD / 4 / 256, 256, 0, stream>>>((const float4*)partial, dvec, (float4*)xbuf);

    // layer 2
    xw_scale<<<N / 64, 256, 0, stream>>>(xbuf, W2, dvec, yT);
    spmm<<<dim3(N / 64, 4), 256, 0, stream>>>(Abf, yT, partial);
    combine_relu<<<N * FD / 4 / 256, 256, 0, stream>>>((const float4*)partial, dvec, (float4*)xbuf);

    // classifier
    logits_k<<<N * NC / 256, 256, 0, stream>>>(xbuf, Wc, bc, out);
}

// Round 2
// 451.470 us; speedup vs baseline: 1.0512x; 1.0512x over previous
//
#include <hip/hip_runtime.h>
#include <stdint.h>

#define N 8192
#define FD 64
#define NC 10
#define SK 8
#define BM 128
#define BK 128

typedef __attribute__((ext_vector_type(8))) __bf16 bf16x8;
typedef __attribute__((ext_vector_type(4))) float f32x4;

__device__ __forceinline__ unsigned short f2bf(float f) {
    unsigned u = __builtin_bit_cast(unsigned, f);
    u += 0x7fffu + ((u >> 16) & 1u);   // round-to-nearest-even
    return (unsigned short)(u >> 16);
}

// async global->LDS, 16B per lane. LDS dest must be wave-uniform base + lane*16.
__device__ __forceinline__ void g2l16(const void* g, void* l) {
    __builtin_amdgcn_global_load_lds(
        (const __attribute__((address_space(1))) unsigned int*)g,
        (__attribute__((address_space(3))) unsigned int*)l, 16, 0, 0);
}

// ---------------------------------------------------------------------------
// Kernel 1: fused row-sum of fp32 A + cast A -> bf16 (RNE). One block per row.
// ---------------------------------------------------------------------------
__global__ __launch_bounds__(256) void rowsum_cast(const float* __restrict__ A,
                                                   unsigned short* __restrict__ Abf,
                                                   float* __restrict__ dvec) {
    const int row = blockIdx.x;
    const int t = threadIdx.x;
    const float4* Arow = (const float4*)(A + (size_t)row * N);
    ushort4* Brow = (ushort4*)(Abf + (size_t)row * N);
    float s = 0.f;
#pragma unroll
    for (int i = 0; i < 8; i++) {
        int c4 = t + 256 * i;
        float4 v = Arow[c4];
        s += (v.x + v.y) + (v.z + v.w);
        ushort4 o;
        o.x = f2bf(v.x); o.y = f2bf(v.y); o.z = f2bf(v.z); o.w = f2bf(v.w);
        Brow[c4] = o;
    }
#pragma unroll
    for (int off = 32; off > 0; off >>= 1) s += __shfl_down(s, off, 64);
    __shared__ float red[4];
    if ((t & 63) == 0) red[t >> 6] = s;
    __syncthreads();
    if (t == 0) {
        float tot = (red[0] + red[1]) + (red[2] + red[3]);
        dvec[row] = tot > 0.f ? rsqrtf(tot) : 0.f;
    }
}

// ---------------------------------------------------------------------------
// Shared inner: per-wave, lane l owns row r0+l, wave w owns f in [16w,16w+16).
// Xs stride 69: bank(l*69+j) = (5l+j)%32 -> 2-way across 64 lanes = free.
// Ws reads are wave-uniform broadcast b128.
// ---------------------------------------------------------------------------
__device__ __forceinline__ void xw_inner(const float (*Xs)[69], const float* Ws,
                                         const float* __restrict__ dvec,
                                         unsigned short* __restrict__ yT,
                                         int r0, int t) {
    const int l = t & 63, w = t >> 6;
    float acc[16];
#pragma unroll
    for (int i = 0; i < 16; i++) acc[i] = 0.f;
#pragma unroll 8
    for (int j = 0; j < 64; j++) {
        float xv = Xs[l][j];
        const float4* wr = (const float4*)(Ws + j * 64 + w * 16);
        float4 w0 = wr[0], w1 = wr[1], w2 = wr[2], w3 = wr[3];
        acc[0] += xv * w0.x; acc[1] += xv * w0.y; acc[2] += xv * w0.z; acc[3] += xv * w0.w;
        acc[4] += xv * w1.x; acc[5] += xv * w1.y; acc[6] += xv * w1.z; acc[7] += xv * w1.w;
        acc[8] += xv * w2.x; acc[9] += xv * w2.y; acc[10] += xv * w2.z; acc[11] += xv * w2.w;
        acc[12] += xv * w3.x; acc[13] += xv * w3.y; acc[14] += xv * w3.z; acc[15] += xv * w3.w;
    }
    float dl = dvec[r0 + l];
#pragma unroll
    for (int ff = 0; ff < 16; ff++)
        yT[(size_t)(w * 16 + ff) * N + r0 + l] = f2bf(dl * acc[ff]);
}

// ---------------------------------------------------------------------------
// Kernel 2 (layer 1): yT[f][r] = bf16( d[r] * (x @ W)[r][f] ), x from global.
// ---------------------------------------------------------------------------
__global__ __launch_bounds__(256) void xw_from_global(const float* __restrict__ x,
                                                      const float* __restrict__ W,
                                                      const float* __restrict__ dvec,
                                                      unsigned short* __restrict__ yT) {
    __shared__ float Xs[64][69];
    __shared__ __align__(16) float Ws[64 * 64];
    const int t = threadIdx.x;
    const int r0 = blockIdx.x * 64;
    const float4* x4 = (const float4*)x + (size_t)r0 * 16;
    const float4* W4 = (const float4*)W;
#pragma unroll
    for (int p = 0; p < 4; p++) {
        int idx = p * 256 + t;
        ((float4*)Ws)[idx] = W4[idx];
        float4 v = x4[idx];
        int row = idx >> 4, f4 = (idx & 15) * 4;
        Xs[row][f4] = v.x; Xs[row][f4 + 1] = v.y; Xs[row][f4 + 2] = v.z; Xs[row][f4 + 3] = v.w;
    }
    __syncthreads();
    xw_inner(Xs, Ws, dvec, yT, r0, t);
}

// ---------------------------------------------------------------------------
// Kernel 3: split-K bf16 MFMA GEMM, BM=128, BK=128, SK=8.
// Staging via global_load_lds(16B); XOR swizzle applied on the GLOBAL address
// (LDS dest stays lane-contiguous). LDS chunk (row,cslot) holds global chunk
// (row, cslot ^ (row&15)), so frag reads at chunk (cc ^ lr) are conflict-free.
// ---------------------------------------------------------------------------
__global__ __launch_bounds__(256) void spmm(const unsigned short* __restrict__ Abf,
                                            const unsigned short* __restrict__ yT,
                                            float* __restrict__ partial) {
    constexpr int KS = N / SK;               // 1024
    __shared__ __align__(16) unsigned short As[BM * BK];   // 32 KB
    __shared__ __align__(16) unsigned short Ys[64 * BK];   // 16 KB
    const int t = threadIdx.x;
    const int m0 = blockIdx.x * BM;
    const int kbase = blockIdx.y * KS;
    const int lane = t & 63, w = t >> 6;
    const int quad = lane >> 4, lr = lane & 15;

    f32x4 acc[2][4];
#pragma unroll
    for (int mt = 0; mt < 2; mt++)
#pragma unroll
        for (int nt = 0; nt < 4; nt++) {
            acc[mt][nt].x = 0.f; acc[mt][nt].y = 0.f; acc[mt][nt].z = 0.f; acc[mt][nt].w = 0.f;
        }

    for (int k0 = kbase; k0 < kbase + KS; k0 += BK) {
#pragma unroll
        for (int p = 0; p < 8; p++) {
            int s = p * 256 + t;
            int row = s >> 4, c = (s & 15) ^ (row & 15);
            g2l16(Abf + (size_t)(m0 + row) * N + k0 + c * 8, As + s * 8);
        }
#pragma unroll
        for (int p = 0; p < 4; p++) {
            int s = p * 256 + t;
            int row = s >> 4, c = (s & 15) ^ (row & 15);
            g2l16(yT + (size_t)row * N + k0 + c * 8, Ys + s * 8);
        }
        __syncthreads();
#pragma unroll
        for (int kk = 0; kk < BK; kk += 32) {
            int cc = (kk >> 3) + quad;
            bf16x8 af0 = *(const bf16x8*)(As + ((w * 32 + lr) * 16 + (cc ^ lr)) * 8);
            bf16x8 af1 = *(const bf16x8*)(As + ((w * 32 + 16 + lr) * 16 + (cc ^ lr)) * 8);
#pragma unroll
            for (int nt = 0; nt < 4; nt++) {
                bf16x8 bv = *(const bf16x8*)(Ys + ((nt * 16 + lr) * 16 + (cc ^ lr)) * 8);
                acc[0][nt] = __builtin_amdgcn_mfma_f32_16x16x32_bf16(af0, bv, acc[0][nt], 0, 0, 0);
                acc[1][nt] = __builtin_amdgcn_mfma_f32_16x16x32_bf16(af1, bv, acc[1][nt], 0, 0, 0);
            }
        }
        __syncthreads();
    }
    // C/D: row = quad*4 + r, col = lr
#pragma unroll
    for (int mt = 0; mt < 2; mt++)
#pragma unroll
        for (int nt = 0; nt < 4; nt++)
#pragma unroll
            for (int r = 0; r < 4; r++) {
                int m = m0 + w * 32 + mt * 16 + quad * 4 + r;
                partial[((size_t)blockIdx.y * N + m) * FD + nt * 16 + lr] = acc[mt][nt][r];
            }
}

// ---------------------------------------------------------------------------
// Kernel 4: fused split-K combine + relu + d-scale + (x @ W2) -> yT (layer 2)
// ---------------------------------------------------------------------------
__global__ __launch_bounds__(256) void combine_xw(const float4* __restrict__ partial4,
                                                  const float* __restrict__ W,
                                                  const float* __restrict__ dvec,
                                                  unsigned short* __restrict__ yT) {
    __shared__ float Xs[64][69];
    __shared__ __align__(16) float Ws[64 * 64];
    const int t = threadIdx.x;
    const int r0 = blockIdx.x * 64;
    const float4* W4 = (const float4*)W;
#pragma unroll
    for (int p = 0; p < 4; p++) {
        int idx = p * 256 + t;
        ((float4*)Ws)[idx] = W4[idx];
        int row = idx >> 4, f4c = idx & 15;
        size_t base = (size_t)(r0 + row) * 16 + f4c;
        float4 s = partial4[base];
#pragma unroll
        for (int sk = 1; sk < SK; sk++) {
            float4 v = partial4[(size_t)sk * (N * 16) + base];
            s.x += v.x; s.y += v.y; s.z += v.z; s.w += v.w;
        }
        float dm = dvec[r0 + row];
        int f4 = f4c * 4;
        Xs[row][f4]     = fmaxf(0.f, dm * s.x);
        Xs[row][f4 + 1] = fmaxf(0.f, dm * s.y);
        Xs[row][f4 + 2] = fmaxf(0.f, dm * s.z);
        Xs[row][f4 + 3] = fmaxf(0.f, dm * s.w);
    }
    __syncthreads();
    xw_inner(Xs, Ws, dvec, yT, r0, t);
}

// ---------------------------------------------------------------------------
// Kernel 5: fused split-K combine + relu + d-scale + classifier (x @ Wc + bc)
// ---------------------------------------------------------------------------
__global__ __launch_bounds__(256) void combine_logits(const float4* __restrict__ partial4,
                                                      const float* __restrict__ dvec,
                                                      const float* __restrict__ Wc,
                                                      const float* __restrict__ bc,
                                                      float* __restrict__ out) {
    __shared__ float Xs[64][69];
    __shared__ float Wcs[64][10];
    __shared__ float bcs[10];
    const int t = threadIdx.x;
    const int r0 = blockIdx.x * 64;
#pragma unroll
    for (int p = 0; p < 4; p++) {
        int idx = p * 256 + t;
        int row = idx >> 4, f4c = idx & 15;
        size_t base = (size_t)(r0 + row) * 16 + f4c;
        float4 s = partial4[base];
#pragma unroll
        for (int sk = 1; sk < SK; sk++) {
            float4 v = partial4[(size_t)sk * (N * 16) + base];
            s.x += v.x; s.y += v.y; s.z += v.z; s.w += v.w;
        }
        float dm = dvec[r0 + row];
        int f4 = f4c * 4;
        Xs[row][f4]     = fmaxf(0.f, dm * s.x);
        Xs[row][f4 + 1] = fmaxf(0.f, dm * s.y);
        Xs[row][f4 + 2] = fmaxf(0.f, dm * s.z);
        Xs[row][f4 + 3] = fmaxf(0.f, dm * s.w);
    }
    for (int i = t; i < 640; i += 256) Wcs[i / 10][i % 10] = Wc[i];
    if (t < 10) bcs[t] = bc[t];
    __syncthreads();
#pragma unroll
    for (int it = 0; it < 3; it++) {
        int idx = it * 256 + t;
        if (idx < 640) {
            int r = idx / 10, c = idx - r * 10;
            float acc = bcs[c];
#pragma unroll
            for (int j = 0; j < 64; j++) acc += Xs[r][j] * Wcs[j][c];
            out[(size_t)(r0 + r) * NC + c] = acc;
        }
    }
}

// ---------------------------------------------------------------------------
extern "C" void kernel_launch(void* const* d_in, const int* in_sizes, int n_in,
                              void* d_out, int out_size, void* d_ws, size_t ws_size,
                              hipStream_t stream) {
    const float* A   = (const float*)d_in[0];
    const float* emb = (const float*)d_in[1];
    const float* W1  = (const float*)d_in[2];
    const float* W2  = (const float*)d_in[3];
    const float* Wc  = (const float*)d_in[4];
    const float* bc  = (const float*)d_in[5];
    char* ws = (char*)d_ws;

    unsigned short* Abf  = (unsigned short*)(ws);                 // 134,217,728 B
    float* dvec          = (float*)(ws + 134217728);              //      32,768 B
    unsigned short* yT   = (unsigned short*)(ws + 134250496);     //   1,048,576 B
    float* partial       = (float*)(ws + 135299072);              //  16,777,216 B (SK=8)
    float* out           = (float*)d_out;

    rowsum_cast<<<N, 256, 0, stream>>>(A, Abf, dvec);

    // layer 1
    xw_from_global<<<N / 64, 256, 0, stream>>>(emb, W1, dvec, yT);
    spmm<<<dim3(N / BM, SK), 256, 0, stream>>>(Abf, yT, partial);

    // layer 2 (combine fused with xw)
    combine_xw<<<N / 64, 256, 0, stream>>>((const float4*)partial, W2, dvec, yT);
    spmm<<<dim3(N / BM, SK), 256, 0, stream>>>(Abf, yT, partial);

    // epilogue (combine fused with classifier)
    combine_logits<<<N / 64, 256, 0, stream>>>((const float4*)partial, dvec, Wc, bc, out);
}

// Round 4
// 428.132 us; speedup vs baseline: 1.1085x; 1.0545x over previous
//
#include <hip/hip_runtime.h>
#include <stdint.h>

#define N 8192
#define FD 64
#define NC 10
#define SK 8
#define BM 128
#define BK 128

typedef __attribute__((ext_vector_type(8))) __bf16 bf16x8;
typedef __attribute__((ext_vector_type(4))) float f32x4;
typedef __attribute__((ext_vector_type(4))) float vf4;   // native vector for nontemporal builtin

__device__ __forceinline__ unsigned short f2bf(float f) {
    unsigned u = __builtin_bit_cast(unsigned, f);
    u += 0x7fffu + ((u >> 16) & 1u);   // round-to-nearest-even
    return (unsigned short)(u >> 16);
}

// async global->LDS, 16B per lane. LDS dest must be wave-uniform base + lane*16.
__device__ __forceinline__ void g2l16(const void* g, void* l) {
    __builtin_amdgcn_global_load_lds(
        (const __attribute__((address_space(1))) unsigned int*)g,
        (__attribute__((address_space(3))) unsigned int*)l, 16, 0, 0);
}

// ---------------------------------------------------------------------------
// Kernel 1: fused row-sum of fp32 A + cast A -> bf16 (RNE). One block per row.
// Nontemporal loads for A: the fp32 stream (268 MB, dead after this kernel)
// must not evict the freshly written Abf (134 MB) from the 256 MB L3 —
// spmm1 wants to read Abf at L3 bandwidth.
// ---------------------------------------------------------------------------
__global__ __launch_bounds__(256) void rowsum_cast(const float* __restrict__ A,
                                                   unsigned short* __restrict__ Abf,
                                                   float* __restrict__ dvec) {
    const int row = blockIdx.x;
    const int t = threadIdx.x;
    const vf4* Arow = (const vf4*)(A + (size_t)row * N);
    ushort4* Brow = (ushort4*)(Abf + (size_t)row * N);
    float s = 0.f;
#pragma unroll
    for (int i = 0; i < 8; i++) {
        int c4 = t + 256 * i;
        vf4 v = __builtin_nontemporal_load(Arow + c4);
        s += (v.x + v.y) + (v.z + v.w);
        ushort4 o;
        o.x = f2bf(v.x); o.y = f2bf(v.y); o.z = f2bf(v.z); o.w = f2bf(v.w);
        Brow[c4] = o;   // regular store: keep Abf L3-resident
    }
#pragma unroll
    for (int off = 32; off > 0; off >>= 1) s += __shfl_down(s, off, 64);
    __shared__ float red[4];
    if ((t & 63) == 0) red[t >> 6] = s;
    __syncthreads();
    if (t == 0) {
        float tot = (red[0] + red[1]) + (red[2] + red[3]);
        dvec[row] = tot > 0.f ? rsqrtf(tot) : 0.f;
    }
}

// ---------------------------------------------------------------------------
// Shared inner: per-wave, lane l owns row r0+l, wave w owns f in [16w,16w+16).
// Xs stride 69: bank(l*69+j) = (5l+j)%32 -> 2-way across 64 lanes = free.
// Ws reads are wave-uniform broadcast b128.
// ---------------------------------------------------------------------------
__device__ __forceinline__ void xw_inner(const float (*Xs)[69], const float* Ws,
                                         const float* __restrict__ dvec,
                                         unsigned short* __restrict__ yT,
                                         int r0, int t) {
    const int l = t & 63, w = t >> 6;
    float acc[16];
#pragma unroll
    for (int i = 0; i < 16; i++) acc[i] = 0.f;
#pragma unroll 8
    for (int j = 0; j < 64; j++) {
        float xv = Xs[l][j];
        const float4* wr = (const float4*)(Ws + j * 64 + w * 16);
        float4 w0 = wr[0], w1 = wr[1], w2 = wr[2], w3 = wr[3];
        acc[0] += xv * w0.x; acc[1] += xv * w0.y; acc[2] += xv * w0.z; acc[3] += xv * w0.w;
        acc[4] += xv * w1.x; acc[5] += xv * w1.y; acc[6] += xv * w1.z; acc[7] += xv * w1.w;
        acc[8] += xv * w2.x; acc[9] += xv * w2.y; acc[10] += xv * w2.z; acc[11] += xv * w2.w;
        acc[12] += xv * w3.x; acc[13] += xv * w3.y; acc[14] += xv * w3.z; acc[15] += xv * w3.w;
    }
    float dl = dvec[r0 + l];
#pragma unroll
    for (int ff = 0; ff < 16; ff++)
        yT[(size_t)(w * 16 + ff) * N + r0 + l] = f2bf(dl * acc[ff]);
}

// ---------------------------------------------------------------------------
// Kernel 2 (layer 1): yT[f][r] = bf16( d[r] * (x @ W)[r][f] ), x from global.
// ---------------------------------------------------------------------------
__global__ __launch_bounds__(256) void xw_from_global(const float* __restrict__ x,
                                                      const float* __restrict__ W,
                                                      const float* __restrict__ dvec,
                                                      unsigned short* __restrict__ yT) {
    __shared__ float Xs[64][69];
    __shared__ __align__(16) float Ws[64 * 64];
    const int t = threadIdx.x;
    const int r0 = blockIdx.x * 64;
    const float4* x4 = (const float4*)x + (size_t)r0 * 16;
    const float4* W4 = (const float4*)W;
#pragma unroll
    for (int p = 0; p < 4; p++) {
        int idx = p * 256 + t;
        ((float4*)Ws)[idx] = W4[idx];
        float4 v = x4[idx];
        int row = idx >> 4, f4 = (idx & 15) * 4;
        Xs[row][f4] = v.x; Xs[row][f4 + 1] = v.y; Xs[row][f4 + 2] = v.z; Xs[row][f4 + 3] = v.w;
    }
    __syncthreads();
    xw_inner(Xs, Ws, dvec, yT, r0, t);
}

// ---------------------------------------------------------------------------
// Kernel 3: split-K bf16 MFMA GEMM, BM=128, BK=128, SK=8.
// Staging via global_load_lds(16B); XOR swizzle applied on the GLOBAL address
// (LDS dest stays lane-contiguous). LDS chunk (row,cslot) holds global chunk
// (row, cslot ^ (row&15)), so frag reads at chunk (cc ^ lr) are conflict-free.
// ---------------------------------------------------------------------------
__global__ __launch_bounds__(256) void spmm(const unsigned short* __restrict__ Abf,
                                            const unsigned short* __restrict__ yT,
                                            float* __restrict__ partial) {
    constexpr int KS = N / SK;               // 1024
    __shared__ __align__(16) unsigned short As[BM * BK];   // 32 KB
    __shared__ __align__(16) unsigned short Ys[64 * BK];   // 16 KB
    const int t = threadIdx.x;
    const int m0 = blockIdx.x * BM;
    const int kbase = blockIdx.y * KS;
    const int lane = t & 63, w = t >> 6;
    const int quad = lane >> 4, lr = lane & 15;

    f32x4 acc[2][4];
#pragma unroll
    for (int mt = 0; mt < 2; mt++)
#pragma unroll
        for (int nt = 0; nt < 4; nt++) {
            acc[mt][nt].x = 0.f; acc[mt][nt].y = 0.f; acc[mt][nt].z = 0.f; acc[mt][nt].w = 0.f;
        }

    for (int k0 = kbase; k0 < kbase + KS; k0 += BK) {
#pragma unroll
        for (int p = 0; p < 8; p++) {
            int s = p * 256 + t;
            int row = s >> 4, c = (s & 15) ^ (row & 15);
            g2l16(Abf + (size_t)(m0 + row) * N + k0 + c * 8, As + s * 8);
        }
#pragma unroll
        for (int p = 0; p < 4; p++) {
            int s = p * 256 + t;
            int row = s >> 4, c = (s & 15) ^ (row & 15);
            g2l16(yT + (size_t)row * N + k0 + c * 8, Ys + s * 8);
        }
        __syncthreads();
#pragma unroll
        for (int kk = 0; kk < BK; kk += 32) {
            int cc = (kk >> 3) + quad;
            bf16x8 af0 = *(const bf16x8*)(As + ((w * 32 + lr) * 16 + (cc ^ lr)) * 8);
            bf16x8 af1 = *(const bf16x8*)(As + ((w * 32 + 16 + lr) * 16 + (cc ^ lr)) * 8);
#pragma unroll
            for (int nt = 0; nt < 4; nt++) {
                bf16x8 bv = *(const bf16x8*)(Ys + ((nt * 16 + lr) * 16 + (cc ^ lr)) * 8);
                acc[0][nt] = __builtin_amdgcn_mfma_f32_16x16x32_bf16(af0, bv, acc[0][nt], 0, 0, 0);
                acc[1][nt] = __builtin_amdgcn_mfma_f32_16x16x32_bf16(af1, bv, acc[1][nt], 0, 0, 0);
            }
        }
        __syncthreads();
    }
    // C/D: row = quad*4 + r, col = lr
#pragma unroll
    for (int mt = 0; mt < 2; mt++)
#pragma unroll
        for (int nt = 0; nt < 4; nt++)
#pragma unroll
            for (int r = 0; r < 4; r++) {
                int m = m0 + w * 32 + mt * 16 + quad * 4 + r;
                partial[((size_t)blockIdx.y * N + m) * FD + nt * 16 + lr] = acc[mt][nt][r];
            }
}

// ---------------------------------------------------------------------------
// Kernel 4: fused split-K combine + relu + d-scale + (x @ W2) -> yT (layer 2)
// ---------------------------------------------------------------------------
__global__ __launch_bounds__(256) void combine_xw(const float4* __restrict__ partial4,
                                                  const float* __restrict__ W,
                                                  const float* __restrict__ dvec,
                                                  unsigned short* __restrict__ yT) {
    __shared__ float Xs[64][69];
    __shared__ __align__(16) float Ws[64 * 64];
    const int t = threadIdx.x;
    const int r0 = blockIdx.x * 64;
    const float4* W4 = (const float4*)W;
#pragma unroll
    for (int p = 0; p < 4; p++) {
        int idx = p * 256 + t;
        ((float4*)Ws)[idx] = W4[idx];
        int row = idx >> 4, f4c = idx & 15;
        size_t base = (size_t)(r0 + row) * 16 + f4c;
        float4 s = partial4[base];
#pragma unroll
        for (int sk = 1; sk < SK; sk++) {
            float4 v = partial4[(size_t)sk * (N * 16) + base];
            s.x += v.x; s.y += v.y; s.z += v.z; s.w += v.w;
        }
        float dm = dvec[r0 + row];
        int f4 = f4c * 4;
        Xs[row][f4]     = fmaxf(0.f, dm * s.x);
        Xs[row][f4 + 1] = fmaxf(0.f, dm * s.y);
        Xs[row][f4 + 2] = fmaxf(0.f, dm * s.z);
        Xs[row][f4 + 3] = fmaxf(0.f, dm * s.w);
    }
    __syncthreads();
    xw_inner(Xs, Ws, dvec, yT, r0, t);
}

// ---------------------------------------------------------------------------
// Kernel 5: fused split-K combine + relu + d-scale + classifier (x @ Wc + bc)
// ---------------------------------------------------------------------------
__global__ __launch_bounds__(256) void combine_logits(const float4* __restrict__ partial4,
                                                      const float* __restrict__ dvec,
                                                      const float* __restrict__ Wc,
                                                      const float* __restrict__ bc,
                                                      float* __restrict__ out) {
    __shared__ float Xs[64][69];
    __shared__ float Wcs[64][10];
    __shared__ float bcs[10];
    const int t = threadIdx.x;
    const int r0 = blockIdx.x * 64;
#pragma unroll
    for (int p = 0; p < 4; p++) {
        int idx = p * 256 + t;
        int row = idx >> 4, f4c = idx & 15;
        size_t base = (size_t)(r0 + row) * 16 + f4c;
        float4 s = partial4[base];
#pragma unroll
        for (int sk = 1; sk < SK; sk++) {
            float4 v = partial4[(size_t)sk * (N * 16) + base];
            s.x += v.x; s.y += v.y; s.z += v.z; s.w += v.w;
        }
        float dm = dvec[r0 + row];
        int f4 = f4c * 4;
        Xs[row][f4]     = fmaxf(0.f, dm * s.x);
        Xs[row][f4 + 1] = fmaxf(0.f, dm * s.y);
        Xs[row][f4 + 2] = fmaxf(0.f, dm * s.z);
        Xs[row][f4 + 3] = fmaxf(0.f, dm * s.w);
    }
    for (int i = t; i < 640; i += 256) Wcs[i / 10][i % 10] = Wc[i];
    if (t < 10) bcs[t] = bc[t];
    __syncthreads();
#pragma unroll
    for (int it = 0; it < 3; it++) {
        int idx = it * 256 + t;
        if (idx < 640) {
            int r = idx / 10, c = idx - r * 10;
            float acc = bcs[c];
#pragma unroll
            for (int j = 0; j < 64; j++) acc += Xs[r][j] * Wcs[j][c];
            out[(size_t)(r0 + r) * NC + c] = acc;
        }
    }
}

// ---------------------------------------------------------------------------
extern "C" void kernel_launch(void* const* d_in, const int* in_sizes, int n_in,
                              void* d_out, int out_size, void* d_ws, size_t ws_size,
                              hipStream_t stream) {
    const float* A   = (const float*)d_in[0];
    const float* emb = (const float*)d_in[1];
    const float* W1  = (const float*)d_in[2];
    const float* W2  = (const float*)d_in[3];
    const float* Wc  = (const float*)d_in[4];
    const float* bc  = (const float*)d_in[5];
    char* ws = (char*)d_ws;

    unsigned short* Abf  = (unsigned short*)(ws);                 // 134,217,728 B
    float* dvec          = (float*)(ws + 134217728);              //      32,768 B
    unsigned short* yT   = (unsigned short*)(ws + 134250496);     //   1,048,576 B
    float* partial       = (float*)(ws + 135299072);              //  16,777,216 B (SK=8)
    float* out           = (float*)d_out;

    rowsum_cast<<<N, 256, 0, stream>>>(A, Abf, dvec);

    // layer 1
    xw_from_global<<<N / 64, 256, 0, stream>>>(emb, W1, dvec, yT);
    spmm<<<dim3(N / BM, SK), 256, 0, stream>>>(Abf, yT, partial);

    // layer 2 (combine fused with xw)
    combine_xw<<<N / 64, 256, 0, stream>>>((const float4*)partial, W2, dvec, yT);
    spmm<<<dim3(N / BM, SK), 256, 0, stream>>>(Abf, yT, partial);

    // epilogue (combine fused with classifier)
    combine_logits<<<N / 64, 256, 0, stream>>>((const float4*)partial, dvec, Wc, bc, out);
}